// Round 6
// baseline (1167.486 us; speedup 1.0000x reference)
//
#include <hip/hip_runtime.h>
#include <hip/hip_bf16.h>
#include <stdint.h>

// Two-phase BiRNN: T=512, B=128, D=H=256, fp32 in/out, bf16 MFMA compute.
//
// Phase A (xw_precompute, 256 blocks x 512 thr, both dirs per block):
//   out[t,b, dir*256+n] = bias[n] + x[t,b,:] @ Wx  (raw fp32 accumulators
//   stored into the output buffer as scratch; phase B overwrites with tanh).
// Phase B (rnn_recur, 8 blocks x 512 thr): TWO independent recurrences per
//   block (batch rows [p*32,p*32+16) for waves 0-3, [p*32+16,p*32+32) for
//   waves 4-7, same dir => shared weights). Each wave owns 64 cols
//   (wfh[4][8] = 128 VGPR). Per barrier-interval the CU-shared LDS pipe
//   moves the same 64KB as before but advances TWO scan steps, and each
//   SIMD carries two data-independent MFMA/trans chains that hide each
//   other's latency. Swapped-operand MFMA (A=Wh^T, B=h) keeps lane output
//   = 4 consecutive cols of one batch row (dwordx4 xw loads/out stores).

typedef short sh8   __attribute__((ext_vector_type(8)));
typedef float f32x4 __attribute__((ext_vector_type(4)));

#define TT 512
#define BB 128
#define HH 256
#define LDH 264   // u16 stride per row: 528 B = 33*16 B (16B-aligned, bank-rotating)

__device__ __forceinline__ unsigned short f2bf(float x) {   // cold paths (weights)
    union { float f; unsigned u; } v; v.f = x;
    unsigned r = v.u + 0x7FFFu + ((v.u >> 16) & 1u);   // RNE
    return (unsigned short)(r >> 16);
}
// hot path: 2x f32 -> packed bf16 (v_cvt_pk_bf16_f32)
__device__ __forceinline__ unsigned pk2bf(float lo, float hi) {
    union { __hip_bfloat162 b; unsigned u; } c;
    c.b = __float22bfloat162_rn(make_float2(lo, hi));
    return c.u;
}
// tanh(x) = 1 - 2/(e^{2x}+1): mul, exp2, add, rcp, fma  (2 trans + 3 VALU)
__device__ __forceinline__ float tanh5(float x) {
    float e = __builtin_amdgcn_exp2f(x * 2.8853900817779268f);   // e^{2x}
    return __builtin_fmaf(-2.0f, __builtin_amdgcn_rcpf(e + 1.0f), 1.0f);
}
// LDS-only barrier: cross-wave communication is exclusively through LDS;
// never drain vmcnt (global stores fire-and-forget, loads reg-consumed).
__device__ __forceinline__ void bar_lds() {
    asm volatile("s_waitcnt lgkmcnt(0)\n\ts_barrier" ::: "memory");
}
__device__ __forceinline__ sh8 pack8(float4 a, float4 b) {
    union { sh8 s; unsigned u[4]; } c;
    c.u[0] = pk2bf(a.x, a.y); c.u[1] = pk2bf(a.z, a.w);
    c.u[2] = pk2bf(b.x, b.y); c.u[3] = pk2bf(b.z, b.w);
    return c.s;
}

// ---------------------------------------------------------------------------
// Phase A: xw = bias + x @ Wx for both directions (x staged once in LDS,
// reused for 2 dirs x 2 col-tiles per wave). Grid 256 = 1 block/CU.
// ---------------------------------------------------------------------------
__global__ __launch_bounds__(512, 2) void xw_precompute(
    const float* __restrict__ x,
    const float* __restrict__ Wxf, const float* __restrict__ bhf,
    const float* __restrict__ Wxb, const float* __restrict__ bhb,
    float* __restrict__ out)
{
    __shared__ __align__(16) unsigned short xb[2][16 * LDH];

    const int tid = threadIdx.x;
    const int w  = tid >> 6, l = tid & 63;
    const int li = l & 15, lq = l >> 4;
    const int N0 = w * 32;
    const int r0 = blockIdx.x * 256;      // rows of T*B = 65536

    // A-operand weight fragments (Wx^T): a[j] = Wx[k][n], k=kf*32+lq*8+j,
    // n = N0 + nt*16 + li
    sh8 wf[2][2][8];
#pragma unroll
    for (int d = 0; d < 2; ++d) {
        const float* W = d ? Wxb : Wxf;
#pragma unroll
        for (int nt = 0; nt < 2; ++nt)
#pragma unroll
            for (int kf = 0; kf < 8; ++kf) {
                sh8 t;
#pragma unroll
                for (int j = 0; j < 8; ++j)
                    t[j] = (short)f2bf(W[(size_t)(kf * 32 + lq * 8 + j) * HH + N0 + nt * 16 + li]);
                wf[d][nt][kf] = t;
            }
    }
    f32x4 bias4[2][2];
#pragma unroll
    for (int d = 0; d < 2; ++d) {
        const float* bs = d ? bhb : bhf;
#pragma unroll
        for (int nt = 0; nt < 2; ++nt)
            bias4[d][nt] = *(const f32x4*)&bs[N0 + nt * 16 + lq * 4];
    }

    // staging: thread -> row sm, 8 cols at sk
    const int sm = tid >> 5;
    const int sk = (tid & 31) * 8;
    const float* xrow = x + (size_t)(r0 + sm) * HH + sk;

    {   // stage tile 0
        float4 v0 = *(const float4*)xrow;
        float4 v1 = *(const float4*)(xrow + 4);
        *(sh8*)&xb[0][sm * LDH + sk] = pack8(v0, v1);
    }
    float4 xg0 = *(const float4*)(xrow + 16 * HH);       // tile 1 in flight
    float4 xg1 = *(const float4*)(xrow + 16 * HH + 4);
    bar_lds();

    // lane's output base: row r0+li, col dir*256 + N0 + lq*4 (+nt*16)
    float* obase = out + (size_t)(r0 + li) * 512 + N0 + lq * 4;

    for (int t = 0; t < 16; ++t) {
        const int cur = t & 1, nxt = cur ^ 1;
        {   // stage tile t+1; kick off load of tile t+2
            *(sh8*)&xb[nxt][sm * LDH + sk] = pack8(xg0, xg1);
            const int t2 = (t + 2 < 16) ? t + 2 : t;     // clamp; tail value unused
            const float* p = xrow + (size_t)t2 * (16 * HH);
            xg0 = *(const float4*)p;
            xg1 = *(const float4*)(p + 4);
        }
        sh8 xf[8];
#pragma unroll
        for (int kf = 0; kf < 8; ++kf)
            xf[kf] = *(const sh8*)&xb[cur][li * LDH + kf * 32 + lq * 8];

        f32x4 acc[2][2];
#pragma unroll
        for (int d = 0; d < 2; ++d)           // kf=0: C = bias (no mov copies)
#pragma unroll
            for (int nt = 0; nt < 2; ++nt)
                acc[d][nt] = __builtin_amdgcn_mfma_f32_16x16x32_bf16(
                    wf[d][nt][0], xf[0], bias4[d][nt], 0, 0, 0);
#pragma unroll
        for (int kf = 1; kf < 8; ++kf)
#pragma unroll
            for (int d = 0; d < 2; ++d)
#pragma unroll
                for (int nt = 0; nt < 2; ++nt)
                    acc[d][nt] = __builtin_amdgcn_mfma_f32_16x16x32_bf16(
                        wf[d][nt][kf], xf[kf], acc[d][nt], 0, 0, 0);

        float* op = obase + (size_t)t * (16 * 512);
#pragma unroll
        for (int d = 0; d < 2; ++d)
#pragma unroll
            for (int nt = 0; nt < 2; ++nt)
                *(f32x4*)(op + d * HH + nt * 16) = acc[d][nt];
        bar_lds();
    }
}

// ---------------------------------------------------------------------------
// Phase B: h_t = tanh(xw_t + h_{t-1} @ Wh), scan over T.
// 8 blocks (4 batch-pairs x 2 dirs) x 512 threads. Waves 0-3: group 0
// (rows pair*32..+16); waves 4-7: group 1 (rows pair*32+16..+32). Each wave
// owns 64 cols. Lane owns batch row (grp base)+li, cols N0+nt*16+lq*4+(0..3).
// ---------------------------------------------------------------------------
__global__ __launch_bounds__(512, 2) void rnn_recur(
    const float* __restrict__ Whf, const float* __restrict__ Whb,
    float* __restrict__ out)
{
    __shared__ __align__(16) unsigned short hb[2][2][16 * LDH]; // [grp][dbuf]

    const int tid = threadIdx.x;
    const int w  = tid >> 6, l = tid & 63;
    const int li = l & 15, lq = l >> 4;
    const int dir  = blockIdx.x >> 2;
    const int grp  = w >> 2;
    const int bbase = (blockIdx.x & 3) * 32 + grp * 16;
    const float* Wh = dir ? Whb : Whf;
    const int N0 = (w & 3) * 64;

    // A-operand fragments of Wh^T (128 VGPRs resident):
    // a[j] = Wh[k][n], k = kf*32+lq*8+j, n = N0 + nt*16 + li
    sh8 wfh[4][8];
#pragma unroll
    for (int nt = 0; nt < 4; ++nt)
#pragma unroll
        for (int kf = 0; kf < 8; ++kf) {
            sh8 t;
#pragma unroll
            for (int j = 0; j < 8; ++j)
                t[j] = (short)f2bf(Wh[(size_t)(kf * 32 + lq * 8 + j) * HH + N0 + nt * 16 + li]);
            wfh[nt][kf] = t;
        }

    // h0 = 0 (both groups, both buffers)
    for (int i = tid; i < 2 * 2 * 16 * LDH / 2; i += 512) ((unsigned*)hb)[i] = 0u;

    const ptrdiff_t ostep = dir ? -(ptrdiff_t)(BB * 512) : (ptrdiff_t)(BB * 512);
    const int t0 = dir ? TT - 1 : 0;
    // lane's rolling out/xw pointer (read xw, overwrite with tanh, same lane)
    float* op = out + (size_t)t0 * (BB * 512)
                    + (size_t)(bbase + li) * 512 + dir * HH + N0 + lq * 4;
    const float* pf = op + 2 * ostep;           // prefetch: xw(s+2)'s address
    float* fsp = out + (size_t)TT * BB * 512 + (size_t)dir * (BB * HH)
                     + (size_t)(bbase + li) * HH + N0 + lq * 4;

    // 2-deep xw prefetch in two NAMED register sets (no runtime indexing)
    f32x4 xA[4], xB[4];
#pragma unroll
    for (int nt = 0; nt < 4; ++nt) {
        xA[nt] = *(const f32x4*)(op + 0 * ostep + nt * 16);
        xB[nt] = *(const f32x4*)(op + 1 * ostep + nt * 16);
    }

    // LDS base pointers (u16 elements), group-private buffers
    const unsigned short* hr0 = &hb[grp][0][li * LDH + lq * 8];        // + kf*32
    const unsigned short* hr1 = &hb[grp][1][li * LDH + lq * 8];
    unsigned short*       hw0 = &hb[grp][0][li * LDH + N0 + lq * 4];   // + nt*16
    unsigned short*       hw1 = &hb[grp][1][li * LDH + N0 + lq * 4];

    bar_lds();

#define STEP(s_, HR, HW, XU)                                                    \
    do {                                                                        \
        sh8 hf[8];                                                              \
        _Pragma("unroll")                                                       \
        for (int kf = 0; kf < 8; ++kf)                                          \
            hf[kf] = *(const sh8*)(HR + kf * 32);                               \
        f32x4 acc[4];                                                           \
        __builtin_amdgcn_s_setprio(1);                                          \
        _Pragma("unroll")                                                       \
        for (int nt = 0; nt < 4; ++nt)   /* kf=0: C = xw (no mov copies) */     \
            acc[nt] = __builtin_amdgcn_mfma_f32_16x16x32_bf16(                  \
                wfh[nt][0], hf[0], XU[nt], 0, 0, 0);                            \
        _Pragma("unroll")                                                       \
        for (int nt = 0; nt < 4; ++nt)   /* refill XU with xw(s+2) */           \
            XU[nt] = *(const f32x4*)(pf + nt * 16);                             \
        pf += ((s_) + 3 < TT) ? ostep : 0;   /* uniform clamp at tail */        \
        _Pragma("unroll")                                                       \
        for (int kf = 1; kf < 8; ++kf)                                          \
            _Pragma("unroll")                                                   \
            for (int nt = 0; nt < 4; ++nt)                                      \
                acc[nt] = __builtin_amdgcn_mfma_f32_16x16x32_bf16(              \
                    wfh[nt][kf], hf[kf], acc[nt], 0, 0, 0);                     \
        __builtin_amdgcn_s_setprio(0);                                          \
        f32x4 vv[4];                                                            \
        _Pragma("unroll")                                                       \
        for (int nt = 0; nt < 4; ++nt) {                                        \
            f32x4 v;                                                            \
            v[0] = tanh5(acc[nt][0]);                                           \
            v[1] = tanh5(acc[nt][1]);                                           \
            v[2] = tanh5(acc[nt][2]);                                           \
            v[3] = tanh5(acc[nt][3]);                                           \
            vv[nt] = v;                                                         \
            *(f32x4*)(op + nt * 16) = v;   /* overwrites consumed xw */         \
            unsigned plo = pk2bf(v[0], v[1]);                                   \
            unsigned phi = pk2bf(v[2], v[3]);                                   \
            *(uint2*)(HW + nt * 16) = make_uint2(plo, phi);                     \
        }                                                                       \
        if ((s_) == TT - 1) {                                                   \
            _Pragma("unroll")                                                   \
            for (int nt = 0; nt < 4; ++nt)                                      \
                *(f32x4*)(fsp + nt * 16) = vv[nt];                              \
        }                                                                       \
        op += ostep;                                                            \
        bar_lds();                                                              \
    } while (0)

    for (int s = 0; s < TT; s += 2) {
        STEP(s,     hr0, hw1, xA);
        STEP(s + 1, hr1, hw0, xB);
    }
#undef STEP
}

extern "C" void kernel_launch(void* const* d_in, const int* in_sizes, int n_in,
                              void* d_out, int out_size, void* d_ws, size_t ws_size,
                              hipStream_t stream)
{
    const float* x   = (const float*)d_in[0];
    const float* Wxf = (const float*)d_in[1];
    const float* Whf = (const float*)d_in[2];
    const float* bhf = (const float*)d_in[3];
    const float* Wxb = (const float*)d_in[4];
    const float* Whb = (const float*)d_in[5];
    const float* bhb = (const float*)d_in[6];

    hipLaunchKernelGGL(xw_precompute, dim3(256), dim3(512), 0, stream,
                       x, Wxf, bhf, Wxb, bhb, (float*)d_out);
    hipLaunchKernelGGL(rnn_recur, dim3(8), dim3(512), 0, stream,
                       Whf, Whb, (float*)d_out);
}

// Round 7
// 752.181 us; speedup vs baseline: 1.5521x; 1.5521x over previous
//
#include <hip/hip_runtime.h>
#include <hip/hip_bf16.h>
#include <stdint.h>

// Two-phase BiRNN: T=512, B=128, D=H=256, fp32 in/out, bf16 MFMA compute.
//
// Phase A (xw_precompute, 512 blocks x 256 thr, NO LDS, NO barriers):
//   out[t,b, dir*256+n] = bias[n] + x[t,b,:] @ Wx  (raw fp32 accumulators
//   stored into the output buffer as scratch; phase B overwrites with tanh).
//   Each wave owns 64 cols (Wx^T frags in 128 VGPRs) and streams 16
//   row-tiles, loading x-frags straight from global (64B-segment coalesced)
//   with a named 2-tile double buffer. 2 blocks/CU, 8 independent
//   wave-streams per CU -- no lockstep phases, loads pipeline freely.
// Phase B (rnn_recur, 16 blocks x 512 thr = 8 waves, 2 waves/SIMD):
//   EXACT round-5 measured-best structure (431 us). Sequential scan
//   h_t = tanh(xw_t + h_{t-1} @ Wh), swapped-operand MFMA (A=Wh^T, B=h),
//   lane owns 4 consecutive output cols of one batch row, 4-deep xw
//   prefetch, s_setprio around the MFMA chain.

typedef short sh8   __attribute__((ext_vector_type(8)));
typedef float f32x4 __attribute__((ext_vector_type(4)));

#define TT 512
#define BB 128
#define HH 256
#define LDH 264   // u16 stride per row: 528 B = 33*16 B (16B-aligned, bank-rotating)

__device__ __forceinline__ unsigned short f2bf(float x) {   // cold paths (weights)
    union { float f; unsigned u; } v; v.f = x;
    unsigned r = v.u + 0x7FFFu + ((v.u >> 16) & 1u);   // RNE
    return (unsigned short)(r >> 16);
}
// hot path: 2x f32 -> packed bf16 (v_cvt_pk_bf16_f32)
__device__ __forceinline__ unsigned pk2bf(float lo, float hi) {
    union { __hip_bfloat162 b; unsigned u; } c;
    c.b = __float22bfloat162_rn(make_float2(lo, hi));
    return c.u;
}
// tanh(x) = 1 - 2/(e^{2x}+1): mul, exp2, add, rcp, fma  (2 trans + 3 VALU)
__device__ __forceinline__ float tanh5(float x) {
    float e = __builtin_amdgcn_exp2f(x * 2.8853900817779268f);   // e^{2x}
    return __builtin_fmaf(-2.0f, __builtin_amdgcn_rcpf(e + 1.0f), 1.0f);
}
// LDS-only barrier: cross-wave communication is exclusively through LDS;
// never drain vmcnt (global stores fire-and-forget, loads reg-consumed).
__device__ __forceinline__ void bar_lds() {
    asm volatile("s_waitcnt lgkmcnt(0)\n\ts_barrier" ::: "memory");
}
__device__ __forceinline__ sh8 pack8(float4 a, float4 b) {
    union { sh8 s; unsigned u[4]; } c;
    c.u[0] = pk2bf(a.x, a.y); c.u[1] = pk2bf(a.z, a.w);
    c.u[2] = pk2bf(b.x, b.y); c.u[3] = pk2bf(b.z, b.w);
    return c.s;
}

// ---------------------------------------------------------------------------
// Phase A: xw = bias + x @ Wx, one direction per block, LDS-free.
// Grid 512 = 256 row-blocks x 2 dirs; 256 thr (4 waves x 64 cols).
// Block: 256 rows of flattened [T*B, D] = 16 tiles of 16 rows, streamed.
// Lane (li,lq): x-frag = x[r0+t*16+li][kf*32+lq*8 .. +8]; output rows r0+t*16+li,
// cols dir*256 + N0 + nt*16 + lq*4 .. +4.
// ---------------------------------------------------------------------------
__global__ __launch_bounds__(256, 2) void xw_precompute(
    const float* __restrict__ x,
    const float* __restrict__ Wxf, const float* __restrict__ bhf,
    const float* __restrict__ Wxb, const float* __restrict__ bhb,
    float* __restrict__ out)
{
    const int tid = threadIdx.x;
    const int w  = tid >> 6, l = tid & 63;
    const int li = l & 15, lq = l >> 4;
    const int dir = blockIdx.x & 1;
    const int r0  = (blockIdx.x >> 1) * 256;     // rows of T*B = 65536
    const float* W  = dir ? Wxb : Wxf;
    const float* bs = dir ? bhb : bhf;
    const int N0 = w * 64;

    // A-operand weight fragments (Wx^T): a[j] = Wx[k][n], k=kf*32+lq*8+j,
    // n = N0 + nt*16 + li  (16-lane segments of 64B -> coalesced gather)
    sh8 wf[4][8];
#pragma unroll
    for (int nt = 0; nt < 4; ++nt)
#pragma unroll
        for (int kf = 0; kf < 8; ++kf) {
            sh8 t;
#pragma unroll
            for (int j = 0; j < 8; ++j)
                t[j] = (short)f2bf(W[(size_t)(kf * 32 + lq * 8 + j) * HH + N0 + nt * 16 + li]);
            wf[nt][kf] = t;
        }
    f32x4 bias4[4];
#pragma unroll
    for (int nt = 0; nt < 4; ++nt)
        bias4[nt] = *(const f32x4*)&bs[N0 + nt * 16 + lq * 4];

    // lane's x base (row r0+li, k-offset lq*8) and out base
    const float* xr = x + (size_t)(r0 + li) * HH + lq * 8;
    float* ob = out + (size_t)(r0 + li) * 512 + dir * HH + N0 + lq * 4;

#define LOADT(t_, XF)                                                           \
    do {                                                                        \
        const float* p_ = xr + (size_t)(t_) * (16 * HH);                        \
        _Pragma("unroll")                                                       \
        for (int kf = 0; kf < 8; ++kf) {                                        \
            float4 a_ = *(const float4*)(p_ + kf * 32);                         \
            float4 b_ = *(const float4*)(p_ + kf * 32 + 4);                     \
            XF[kf] = pack8(a_, b_);                                             \
        }                                                                       \
    } while (0)

#define COMPT(t_, XF)                                                           \
    do {                                                                        \
        f32x4 acc[4];                                                           \
        _Pragma("unroll")                                                       \
        for (int nt = 0; nt < 4; ++nt)      /* kf=0: C = bias */                \
            acc[nt] = __builtin_amdgcn_mfma_f32_16x16x32_bf16(                  \
                wf[nt][0], XF[0], bias4[nt], 0, 0, 0);                          \
        _Pragma("unroll")                                                       \
        for (int kf = 1; kf < 8; ++kf)                                          \
            _Pragma("unroll")                                                   \
            for (int nt = 0; nt < 4; ++nt)                                      \
                acc[nt] = __builtin_amdgcn_mfma_f32_16x16x32_bf16(              \
                    wf[nt][kf], XF[kf], acc[nt], 0, 0, 0);                      \
        float* op_ = ob + (size_t)(t_) * (16 * 512);                            \
        _Pragma("unroll")                                                       \
        for (int nt = 0; nt < 4; ++nt)                                          \
            *(f32x4*)(op_ + nt * 16) = acc[nt];                                 \
    } while (0)

    sh8 xfA[8], xfB[8];
    LOADT(0, xfA);
#pragma unroll
    for (int t = 0; t < 16; t += 2) {
        if (t + 1 < 16) LOADT(t + 1, xfB);
        COMPT(t, xfA);
        if (t + 2 < 16) LOADT(t + 2, xfA);
        COMPT(t + 1, xfB);
    }
#undef LOADT
#undef COMPT
}

// ---------------------------------------------------------------------------
// Phase B: h_t = tanh(xw_t + h_{t-1} @ Wh), scan over T.
// 16 blocks (8 batch-groups x 2 dirs) x 512 threads (8 waves, 32 cols/wave,
// 2 waves/SIMD). Lane owns batch row bbase+li, cols N0 + nt*16 + lq*4 (+0..3).
// EXACT round-5 measured configuration (431 us).
// ---------------------------------------------------------------------------
__global__ __launch_bounds__(512, 2) void rnn_recur(
    const float* __restrict__ Whf, const float* __restrict__ Whb,
    float* __restrict__ out)
{
    __shared__ __align__(16) unsigned short hb[2][16 * LDH];   // h state, bf16

    const int tid = threadIdx.x;
    const int w  = tid >> 6, l = tid & 63;
    const int li = l & 15, lq = l >> 4;
    const int dir   = blockIdx.x >> 3;
    const int bbase = (blockIdx.x & 7) * 16;
    const float* Wh = dir ? Whb : Whf;
    const int N0 = w * 32;

    // A-operand fragments of Wh^T (64 VGPRs resident):
    // a[j] = Wh[k][n], k = kf*32+lq*8+j, n = N0 + nt*16 + li
    sh8 wfh[2][8];
#pragma unroll
    for (int nt = 0; nt < 2; ++nt)
#pragma unroll
        for (int kf = 0; kf < 8; ++kf) {
            sh8 t;
#pragma unroll
            for (int j = 0; j < 8; ++j)
                t[j] = (short)f2bf(Wh[(size_t)(kf * 32 + lq * 8 + j) * HH + N0 + nt * 16 + li]);
            wfh[nt][kf] = t;
        }

    // h0 = 0
    for (int i = tid; i < 16 * LDH / 2; i += 512) ((unsigned*)hb[0])[i] = 0u;

    const ptrdiff_t ostep = dir ? -(ptrdiff_t)(BB * 512) : (ptrdiff_t)(BB * 512);
    const int t0 = dir ? TT - 1 : 0;
    // lane's rolling out/xw pointer (read xw, overwrite with tanh, same lane)
    float* op = out + (size_t)t0 * (BB * 512)
                    + (size_t)(bbase + li) * 512 + dir * HH + N0 + lq * 4;
    const float* pf = op + 4 * ostep;           // prefetch: xw(s+4)'s address
    float* fsp = out + (size_t)TT * BB * 512 + (size_t)dir * (BB * HH)
                     + (size_t)(bbase + li) * HH + N0 + lq * 4;

    // 4-deep xw prefetch in four NAMED register sets (no runtime indexing)
    f32x4 xA[2], xB[2], xC[2], xD[2];
#pragma unroll
    for (int nt = 0; nt < 2; ++nt) {
        xA[nt] = *(const f32x4*)(op + 0 * ostep + nt * 16);
        xB[nt] = *(const f32x4*)(op + 1 * ostep + nt * 16);
        xC[nt] = *(const f32x4*)(op + 2 * ostep + nt * 16);
        xD[nt] = *(const f32x4*)(op + 3 * ostep + nt * 16);
    }

    // LDS base pointers (u16 elements)
    const unsigned short* hr0 = &hb[0][li * LDH + lq * 8];        // + kf*32
    const unsigned short* hr1 = &hb[1][li * LDH + lq * 8];
    unsigned short*       hw0 = &hb[0][li * LDH + N0 + lq * 4];   // + nt*16
    unsigned short*       hw1 = &hb[1][li * LDH + N0 + lq * 4];

    bar_lds();

#define STEP(s_, HR, HW, XU)                                                    \
    do {                                                                        \
        sh8 hf[8];                                                              \
        _Pragma("unroll")                                                       \
        for (int kf = 0; kf < 8; ++kf)                                          \
            hf[kf] = *(const sh8*)(HR + kf * 32);                               \
        f32x4 acc[2];                                                           \
        __builtin_amdgcn_s_setprio(1);                                          \
        _Pragma("unroll")                                                       \
        for (int nt = 0; nt < 2; ++nt)   /* kf=0: C = xw (no mov copies) */     \
            acc[nt] = __builtin_amdgcn_mfma_f32_16x16x32_bf16(                  \
                wfh[nt][0], hf[0], XU[nt], 0, 0, 0);                            \
        _Pragma("unroll")                                                       \
        for (int nt = 0; nt < 2; ++nt)   /* refill XU with xw(s+4) */           \
            XU[nt] = *(const f32x4*)(pf + nt * 16);                             \
        pf += ((s_) + 5 < TT) ? ostep : 0;   /* uniform clamp at tail */        \
        _Pragma("unroll")                                                       \
        for (int kf = 1; kf < 8; ++kf)                                          \
            _Pragma("unroll")                                                   \
            for (int nt = 0; nt < 2; ++nt)                                      \
                acc[nt] = __builtin_amdgcn_mfma_f32_16x16x32_bf16(              \
                    wfh[nt][kf], hf[kf], acc[nt], 0, 0, 0);                     \
        __builtin_amdgcn_s_setprio(0);                                          \
        f32x4 vv[2];                                                            \
        _Pragma("unroll")                                                       \
        for (int nt = 0; nt < 2; ++nt) {                                        \
            f32x4 v;                                                            \
            v[0] = tanh5(acc[nt][0]);                                           \
            v[1] = tanh5(acc[nt][1]);                                           \
            v[2] = tanh5(acc[nt][2]);                                           \
            v[3] = tanh5(acc[nt][3]);                                           \
            vv[nt] = v;                                                         \
            *(f32x4*)(op + nt * 16) = v;   /* overwrites consumed xw */         \
            unsigned plo = pk2bf(v[0], v[1]);                                   \
            unsigned phi = pk2bf(v[2], v[3]);                                   \
            *(uint2*)(HW + nt * 16) = make_uint2(plo, phi);                     \
        }                                                                       \
        if ((s_) == TT - 1) {                                                   \
            _Pragma("unroll")                                                   \
            for (int nt = 0; nt < 2; ++nt)                                      \
                *(f32x4*)(fsp + nt * 16) = vv[nt];                              \
        }                                                                       \
        op += ostep;                                                            \
        bar_lds();                                                              \
    } while (0)

    for (int s = 0; s < TT; s += 4) {
        STEP(s,     hr0, hw1, xA);
        STEP(s + 1, hr1, hw0, xB);
        STEP(s + 2, hr0, hw1, xC);
        STEP(s + 3, hr1, hw0, xD);
    }
#undef STEP
}

extern "C" void kernel_launch(void* const* d_in, const int* in_sizes, int n_in,
                              void* d_out, int out_size, void* d_ws, size_t ws_size,
                              hipStream_t stream)
{
    const float* x   = (const float*)d_in[0];
    const float* Wxf = (const float*)d_in[1];
    const float* Whf = (const float*)d_in[2];
    const float* bhf = (const float*)d_in[3];
    const float* Wxb = (const float*)d_in[4];
    const float* Whb = (const float*)d_in[5];
    const float* bhb = (const float*)d_in[6];

    hipLaunchKernelGGL(xw_precompute, dim3(512), dim3(256), 0, stream,
                       x, Wxf, bhf, Wxb, bhb, (float*)d_out);
    hipLaunchKernelGGL(rnn_recur, dim3(16), dim3(512), 0, stream,
                       Whf, Whb, (float*)d_out);
}

// Round 8
// 633.819 us; speedup vs baseline: 1.8420x; 1.1867x over previous
//
#include <hip/hip_runtime.h>
#include <hip/hip_bf16.h>
#include <stdint.h>

// Two-phase BiRNN: T=512, B=128, D=H=256, fp32 in/out, bf16 MFMA compute.
//
// Phase A (xw_precompute, 256 blocks x 512 thr, both dirs fused, LDS-staged):
//   MEASURED-BEST variant (~176 us, round 2). out[t,b,dir*256+n] = bias[n] +
//   x[t,b,:] @ Wx, raw fp32 accumulators stored into out as scratch.
// Phase B (rnn_recur, 16 blocks x 512 thr = 8 waves, 2 waves/SIMD):
//   round-5 measured structure (431 us) + MFMA chain split: each nt-column
//   accumulator is two independent 4-deep chains (kf0-3 seeded with xw,
//   kf4-7 seeded with a persistent zero reg), summed at the end -> 8
//   independent chains/SIMD to cover MFMA latency. Everything else
//   unchanged: swapped-operand MFMA (A=Wh^T, B=h), lane owns 4 consecutive
//   output cols of one batch row, 4-deep xw prefetch, setprio around MFMA.

typedef short sh8   __attribute__((ext_vector_type(8)));
typedef float f32x4 __attribute__((ext_vector_type(4)));

#define TT 512
#define BB 128
#define HH 256
#define LDH 264   // u16 stride per row: 528 B = 33*16 B (16B-aligned, bank-rotating)

__device__ __forceinline__ unsigned short f2bf(float x) {   // cold paths (weights)
    union { float f; unsigned u; } v; v.f = x;
    unsigned r = v.u + 0x7FFFu + ((v.u >> 16) & 1u);   // RNE
    return (unsigned short)(r >> 16);
}
// hot path: 2x f32 -> packed bf16 (v_cvt_pk_bf16_f32)
__device__ __forceinline__ unsigned pk2bf(float lo, float hi) {
    union { __hip_bfloat162 b; unsigned u; } c;
    c.b = __float22bfloat162_rn(make_float2(lo, hi));
    return c.u;
}
// tanh(x) = 1 - 2/(e^{2x}+1): mul, exp2, add, rcp, fma  (2 trans + 3 VALU)
__device__ __forceinline__ float tanh5(float x) {
    float e = __builtin_amdgcn_exp2f(x * 2.8853900817779268f);   // e^{2x}
    return __builtin_fmaf(-2.0f, __builtin_amdgcn_rcpf(e + 1.0f), 1.0f);
}
// LDS-only barrier: cross-wave communication is exclusively through LDS;
// never drain vmcnt (global stores fire-and-forget, loads reg-consumed).
__device__ __forceinline__ void bar_lds() {
    asm volatile("s_waitcnt lgkmcnt(0)\n\ts_barrier" ::: "memory");
}
__device__ __forceinline__ sh8 pack8(float4 a, float4 b) {
    union { sh8 s; unsigned u[4]; } c;
    c.u[0] = pk2bf(a.x, a.y); c.u[1] = pk2bf(a.z, a.w);
    c.u[2] = pk2bf(b.x, b.y); c.u[3] = pk2bf(b.z, b.w);
    return c.s;
}

// ---------------------------------------------------------------------------
// Phase A: xw = bias + x @ Wx for both directions, full-chip GEMM.
// 256 blocks x 512 thr (8 waves). Block: 256 rows of flattened [T*B, D] =
// 16 tiles of 16 rows, both directions (x staged once, reused 2dir x 2nt).
// MEASURED: ~176 us (round 2). Do not restructure without A/B evidence.
// ---------------------------------------------------------------------------
__global__ __launch_bounds__(512, 2) void xw_precompute(
    const float* __restrict__ x,
    const float* __restrict__ Wxf, const float* __restrict__ bhf,
    const float* __restrict__ Wxb, const float* __restrict__ bhb,
    float* __restrict__ out)
{
    __shared__ __align__(16) unsigned short xb[2][16 * LDH];

    const int tid = threadIdx.x;
    const int w  = tid >> 6, l = tid & 63;
    const int li = l & 15, lq = l >> 4;
    const int N0 = w * 32;
    const int r0 = blockIdx.x * 256;      // rows of T*B = 65536

    // A-operand weight fragments (Wx^T): a[j] = Wx[k][n], k=kf*32+lq*8+j,
    // n = N0 + nt*16 + li
    sh8 wf[2][2][8];
#pragma unroll
    for (int d = 0; d < 2; ++d) {
        const float* W = d ? Wxb : Wxf;
#pragma unroll
        for (int nt = 0; nt < 2; ++nt)
#pragma unroll
            for (int kf = 0; kf < 8; ++kf) {
                sh8 t;
#pragma unroll
                for (int j = 0; j < 8; ++j)
                    t[j] = (short)f2bf(W[(size_t)(kf * 32 + lq * 8 + j) * HH + N0 + nt * 16 + li]);
                wf[d][nt][kf] = t;
            }
    }
    f32x4 bias4[2][2];
#pragma unroll
    for (int d = 0; d < 2; ++d) {
        const float* bs = d ? bhb : bhf;
#pragma unroll
        for (int nt = 0; nt < 2; ++nt)
            bias4[d][nt] = *(const f32x4*)&bs[N0 + nt * 16 + lq * 4];
    }

    // staging: thread -> row sm, 8 cols at sk
    const int sm = tid >> 5;
    const int sk = (tid & 31) * 8;
    const float* xrow = x + (size_t)(r0 + sm) * HH + sk;

    {   // stage tile 0
        float4 v0 = *(const float4*)xrow;
        float4 v1 = *(const float4*)(xrow + 4);
        *(sh8*)&xb[0][sm * LDH + sk] = pack8(v0, v1);
    }
    float4 xg0 = *(const float4*)(xrow + 16 * HH);       // tile 1 in flight
    float4 xg1 = *(const float4*)(xrow + 16 * HH + 4);
    bar_lds();

    // lane's output base: row r0+li, col dir*256 + N0 + lq*4 (+nt*16)
    float* obase = out + (size_t)(r0 + li) * 512 + N0 + lq * 4;

    for (int t = 0; t < 16; ++t) {
        const int cur = t & 1, nxt = cur ^ 1;
        {   // stage tile t+1; kick off load of tile t+2
            *(sh8*)&xb[nxt][sm * LDH + sk] = pack8(xg0, xg1);
            const int t2 = (t + 2 < 16) ? t + 2 : t;     // clamp; tail value unused
            const float* p = xrow + (size_t)t2 * (16 * HH);
            xg0 = *(const float4*)p;
            xg1 = *(const float4*)(p + 4);
        }
        sh8 xf[8];
#pragma unroll
        for (int kf = 0; kf < 8; ++kf)
            xf[kf] = *(const sh8*)&xb[cur][li * LDH + kf * 32 + lq * 8];

        f32x4 acc[2][2];
#pragma unroll
        for (int d = 0; d < 2; ++d)           // kf=0: C = bias (no mov copies)
#pragma unroll
            for (int nt = 0; nt < 2; ++nt)
                acc[d][nt] = __builtin_amdgcn_mfma_f32_16x16x32_bf16(
                    wf[d][nt][0], xf[0], bias4[d][nt], 0, 0, 0);
#pragma unroll
        for (int kf = 1; kf < 8; ++kf)
#pragma unroll
            for (int d = 0; d < 2; ++d)
#pragma unroll
                for (int nt = 0; nt < 2; ++nt)
                    acc[d][nt] = __builtin_amdgcn_mfma_f32_16x16x32_bf16(
                        wf[d][nt][kf], xf[kf], acc[d][nt], 0, 0, 0);

        float* op = obase + (size_t)t * (16 * 512);
#pragma unroll
        for (int d = 0; d < 2; ++d)
#pragma unroll
            for (int nt = 0; nt < 2; ++nt)
                *(f32x4*)(op + d * HH + nt * 16) = acc[d][nt];
        bar_lds();
    }
}

// ---------------------------------------------------------------------------
// Phase B: h_t = tanh(xw_t + h_{t-1} @ Wh), scan over T.
// 16 blocks (8 batch-groups x 2 dirs) x 512 threads (8 waves, 32 cols/wave,
// 2 waves/SIMD). Lane owns batch row bbase+li, cols N0 + nt*16 + lq*4 (+0..3).
// Round-5 measured config + split accumulation chains (4-deep x 2).
// ---------------------------------------------------------------------------
__global__ __launch_bounds__(512, 2) void rnn_recur(
    const float* __restrict__ Whf, const float* __restrict__ Whb,
    float* __restrict__ out)
{
    __shared__ __align__(16) unsigned short hb[2][16 * LDH];   // h state, bf16

    const int tid = threadIdx.x;
    const int w  = tid >> 6, l = tid & 63;
    const int li = l & 15, lq = l >> 4;
    const int dir   = blockIdx.x >> 3;
    const int bbase = (blockIdx.x & 7) * 16;
    const float* Wh = dir ? Whb : Whf;
    const int N0 = w * 32;

    // A-operand fragments of Wh^T (64 VGPRs resident):
    // a[j] = Wh[k][n], k = kf*32+lq*8+j, n = N0 + nt*16 + li
    sh8 wfh[2][8];
#pragma unroll
    for (int nt = 0; nt < 2; ++nt)
#pragma unroll
        for (int kf = 0; kf < 8; ++kf) {
            sh8 t;
#pragma unroll
            for (int j = 0; j < 8; ++j)
                t[j] = (short)f2bf(Wh[(size_t)(kf * 32 + lq * 8 + j) * HH + N0 + nt * 16 + li]);
            wfh[nt][kf] = t;
        }

    // h0 = 0
    for (int i = tid; i < 16 * LDH / 2; i += 512) ((unsigned*)hb[0])[i] = 0u;

    const ptrdiff_t ostep = dir ? -(ptrdiff_t)(BB * 512) : (ptrdiff_t)(BB * 512);
    const int t0 = dir ? TT - 1 : 0;
    // lane's rolling out/xw pointer (read xw, overwrite with tanh, same lane)
    float* op = out + (size_t)t0 * (BB * 512)
                    + (size_t)(bbase + li) * 512 + dir * HH + N0 + lq * 4;
    const float* pf = op + 4 * ostep;           // prefetch: xw(s+4)'s address
    float* fsp = out + (size_t)TT * BB * 512 + (size_t)dir * (BB * HH)
                     + (size_t)(bbase + li) * HH + N0 + lq * 4;

    // 4-deep xw prefetch in four NAMED register sets (no runtime indexing)
    f32x4 xA[2], xB[2], xC[2], xD[2];
#pragma unroll
    for (int nt = 0; nt < 2; ++nt) {
        xA[nt] = *(const f32x4*)(op + 0 * ostep + nt * 16);
        xB[nt] = *(const f32x4*)(op + 1 * ostep + nt * 16);
        xC[nt] = *(const f32x4*)(op + 2 * ostep + nt * 16);
        xD[nt] = *(const f32x4*)(op + 3 * ostep + nt * 16);
    }
    const f32x4 zero4 = (f32x4){0.f, 0.f, 0.f, 0.f};   // persistent C-seed

    // LDS base pointers (u16 elements)
    const unsigned short* hr0 = &hb[0][li * LDH + lq * 8];        // + kf*32
    const unsigned short* hr1 = &hb[1][li * LDH + lq * 8];
    unsigned short*       hw0 = &hb[0][li * LDH + N0 + lq * 4];   // + nt*16
    unsigned short*       hw1 = &hb[1][li * LDH + N0 + lq * 4];

    bar_lds();

#define STEP(s_, HR, HW, XU)                                                    \
    do {                                                                        \
        sh8 hf[8];                                                              \
        _Pragma("unroll")                                                       \
        for (int kf = 0; kf < 8; ++kf)                                          \
            hf[kf] = *(const sh8*)(HR + kf * 32);                               \
        f32x4 acc[2], acd[2];                                                   \
        __builtin_amdgcn_s_setprio(1);                                          \
        _Pragma("unroll")                                                       \
        for (int nt = 0; nt < 2; ++nt) {  /* chain heads: C=xw and C=0 */       \
            acc[nt] = __builtin_amdgcn_mfma_f32_16x16x32_bf16(                  \
                wfh[nt][0], hf[0], XU[nt], 0, 0, 0);                            \
            acd[nt] = __builtin_amdgcn_mfma_f32_16x16x32_bf16(                  \
                wfh[nt][4], hf[4], zero4, 0, 0, 0);                             \
        }                                                                       \
        _Pragma("unroll")                                                       \
        for (int nt = 0; nt < 2; ++nt)   /* refill XU with xw(s+4) */           \
            XU[nt] = *(const f32x4*)(pf + nt * 16);                             \
        pf += ((s_) + 5 < TT) ? ostep : 0;   /* uniform clamp at tail */        \
        _Pragma("unroll")                                                       \
        for (int kf = 1; kf < 4; ++kf)                                          \
            _Pragma("unroll")                                                   \
            for (int nt = 0; nt < 2; ++nt) {                                    \
                acc[nt] = __builtin_amdgcn_mfma_f32_16x16x32_bf16(              \
                    wfh[nt][kf], hf[kf], acc[nt], 0, 0, 0);                     \
                acd[nt] = __builtin_amdgcn_mfma_f32_16x16x32_bf16(              \
                    wfh[nt][kf + 4], hf[kf + 4], acd[nt], 0, 0, 0);             \
            }                                                                   \
        __builtin_amdgcn_s_setprio(0);                                          \
        f32x4 vv[2];                                                            \
        _Pragma("unroll")                                                       \
        for (int nt = 0; nt < 2; ++nt) {                                        \
            f32x4 v;                                                            \
            v[0] = tanh5(acc[nt][0] + acd[nt][0]);                              \
            v[1] = tanh5(acc[nt][1] + acd[nt][1]);                              \
            v[2] = tanh5(acc[nt][2] + acd[nt][2]);                              \
            v[3] = tanh5(acc[nt][3] + acd[nt][3]);                              \
            vv[nt] = v;                                                         \
            *(f32x4*)(op + nt * 16) = v;   /* overwrites consumed xw */         \
            unsigned plo = pk2bf(v[0], v[1]);                                   \
            unsigned phi = pk2bf(v[2], v[3]);                                   \
            *(uint2*)(HW + nt * 16) = make_uint2(plo, phi);                     \
        }                                                                       \
        if ((s_) == TT - 1) {                                                   \
            _Pragma("unroll")                                                   \
            for (int nt = 0; nt < 2; ++nt)                                      \
                *(f32x4*)(fsp + nt * 16) = vv[nt];                              \
        }                                                                       \
        op += ostep;                                                            \
        bar_lds();                                                              \
    } while (0)

    for (int s = 0; s < TT; s += 4) {
        STEP(s,     hr0, hw1, xA);
        STEP(s + 1, hr1, hw0, xB);
        STEP(s + 2, hr0, hw1, xC);
        STEP(s + 3, hr1, hw0, xD);
    }
#undef STEP
}

extern "C" void kernel_launch(void* const* d_in, const int* in_sizes, int n_in,
                              void* d_out, int out_size, void* d_ws, size_t ws_size,
                              hipStream_t stream)
{
    const float* x   = (const float*)d_in[0];
    const float* Wxf = (const float*)d_in[1];
    const float* Whf = (const float*)d_in[2];
    const float* bhf = (const float*)d_in[3];
    const float* Wxb = (const float*)d_in[4];
    const float* Whb = (const float*)d_in[5];
    const float* bhb = (const float*)d_in[6];

    hipLaunchKernelGGL(xw_precompute, dim3(256), dim3(512), 0, stream,
                       x, Wxf, bhf, Wxb, bhb, (float*)d_out);
    hipLaunchKernelGGL(rnn_recur, dim3(16), dim3(512), 0, stream,
                       Whf, Whb, (float*)d_out);
}

// Round 9
// 581.889 us; speedup vs baseline: 2.0064x; 1.0892x over previous
//
#include <hip/hip_runtime.h>
#include <hip/hip_bf16.h>
#include <stdint.h>

// Two-phase BiRNN: T=512, B=128, D=H=256, fp32 in/out, bf16 MFMA compute.
//
// Phase A (xw_precompute, 256 blocks x 512 thr, both dirs fused, LDS-staged):
//   xw[t,b,dir,n] = bias[n] + x[t,b,:] @ Wx. Stored (when ws permits) into
//   d_ws in a WAVE-CONTIGUOUS permuted layout: chunk(t,g,dir,w,nt) of 1KB,
//   lane l at +l*16B  ->  one fully-coalesced 1KB dwordx4 per wave-store
//   (the canonical 16B-strided store pattern was the ~176us limiter).
//   Fallback (ws too small): store canonical into out (in-place scheme).
// Phase B (rnn_recur, 16 blocks x 512 thr = 8 waves, 2 waves/SIMD):
//   R5/R8 measured structure. Scan h_t = tanh(xw_t + h_{t-1} @ Wh),
//   swapped-operand MFMA (A=Wh^T, B=h), lane owns 4 consecutive out cols of
//   one batch row, 4-deep xw prefetch (coalesced 1KB chunks when perm),
//   split accumulation chains, setprio around MFMA. Stores to out canonical.

typedef short sh8   __attribute__((ext_vector_type(8)));
typedef float f32x4 __attribute__((ext_vector_type(4)));

#define TT 512
#define BB 128
#define HH 256
#define LDH 264   // u16 stride per row: 528 B = 33*16 B (16B-aligned, bank-rotating)

__device__ __forceinline__ unsigned short f2bf(float x) {   // cold paths (weights)
    union { float f; unsigned u; } v; v.f = x;
    unsigned r = v.u + 0x7FFFu + ((v.u >> 16) & 1u);   // RNE
    return (unsigned short)(r >> 16);
}
// hot path: 2x f32 -> packed bf16 (v_cvt_pk_bf16_f32)
__device__ __forceinline__ unsigned pk2bf(float lo, float hi) {
    union { __hip_bfloat162 b; unsigned u; } c;
    c.b = __float22bfloat162_rn(make_float2(lo, hi));
    return c.u;
}
// tanh(x) = 1 - 2/(e^{2x}+1): mul, exp2, add, rcp, fma  (2 trans + 3 VALU)
__device__ __forceinline__ float tanh5(float x) {
    float e = __builtin_amdgcn_exp2f(x * 2.8853900817779268f);   // e^{2x}
    return __builtin_fmaf(-2.0f, __builtin_amdgcn_rcpf(e + 1.0f), 1.0f);
}
// LDS-only barrier: cross-wave communication is exclusively through LDS;
// never drain vmcnt (global stores fire-and-forget, loads reg-consumed).
__device__ __forceinline__ void bar_lds() {
    asm volatile("s_waitcnt lgkmcnt(0)\n\ts_barrier" ::: "memory");
}
__device__ __forceinline__ sh8 pack8(float4 a, float4 b) {
    union { sh8 s; unsigned u[4]; } c;
    c.u[0] = pk2bf(a.x, a.y); c.u[1] = pk2bf(a.z, a.w);
    c.u[2] = pk2bf(b.x, b.y); c.u[3] = pk2bf(b.z, b.w);
    return c.s;
}

// ---------------------------------------------------------------------------
// Phase A: xw = bias + x @ Wx for both directions, full-chip GEMM.
// 256 blocks x 512 thr (8 waves). Block: 256 rows of flattened [T*B, D] =
// 16 tiles of 16 rows, both directions (x staged once, reused 2dir x 2nt).
// perm=1: store to xws chunks (coalesced 1KB/wave); perm=0: canonical out.
// ---------------------------------------------------------------------------
__global__ __launch_bounds__(512, 2) void xw_precompute(
    const float* __restrict__ x,
    const float* __restrict__ Wxf, const float* __restrict__ bhf,
    const float* __restrict__ Wxb, const float* __restrict__ bhb,
    float* __restrict__ out, float* __restrict__ xws, int perm)
{
    __shared__ __align__(16) unsigned short xb[2][16 * LDH];

    const int tid = threadIdx.x;
    const int w  = tid >> 6, l = tid & 63;
    const int li = l & 15, lq = l >> 4;
    const int N0 = w * 32;
    const int r0 = blockIdx.x * 256;      // rows of T*B = 65536

    // A-operand weight fragments (Wx^T): a[j] = Wx[k][n], k=kf*32+lq*8+j,
    // n = N0 + nt*16 + li
    sh8 wf[2][2][8];
#pragma unroll
    for (int d = 0; d < 2; ++d) {
        const float* W = d ? Wxb : Wxf;
#pragma unroll
        for (int nt = 0; nt < 2; ++nt)
#pragma unroll
            for (int kf = 0; kf < 8; ++kf) {
                sh8 t;
#pragma unroll
                for (int j = 0; j < 8; ++j)
                    t[j] = (short)f2bf(W[(size_t)(kf * 32 + lq * 8 + j) * HH + N0 + nt * 16 + li]);
                wf[d][nt][kf] = t;
            }
    }
    f32x4 bias4[2][2];
#pragma unroll
    for (int d = 0; d < 2; ++d) {
        const float* bs = d ? bhb : bhf;
#pragma unroll
        for (int nt = 0; nt < 2; ++nt)
            bias4[d][nt] = *(const f32x4*)&bs[N0 + nt * 16 + lq * 4];
    }

    // staging: thread -> row sm, 8 cols at sk
    const int sm = tid >> 5;
    const int sk = (tid & 31) * 8;
    const float* xrow = x + (size_t)(r0 + sm) * HH + sk;

    {   // stage tile 0
        float4 v0 = *(const float4*)xrow;
        float4 v1 = *(const float4*)(xrow + 4);
        *(sh8*)&xb[0][sm * LDH + sk] = pack8(v0, v1);
    }
    float4 xg0 = *(const float4*)(xrow + 16 * HH);       // tile 1 in flight
    float4 xg1 = *(const float4*)(xrow + 16 * HH + 4);
    bar_lds();

    // canonical out base: row r0+li, col dir*256 + N0 + lq*4 (+nt*16)
    float* obase = out + (size_t)(r0 + li) * 512 + N0 + lq * 4;
    // permuted ws base per dir: chunk = ((r0/16+t)*2+d)*8+w)*2+nt, lane l
    // -> float offset (r0/16+t)*8192 + d*4096 + w*512 + nt*256 + l*4
    float* cp0 = xws + (size_t)(r0 / 16) * 8192 + 0 * 4096 + w * 512 + (size_t)l * 4;
    float* cp1 = xws + (size_t)(r0 / 16) * 8192 + 1 * 4096 + w * 512 + (size_t)l * 4;

    for (int t = 0; t < 16; ++t) {
        const int cur = t & 1, nxt = cur ^ 1;
        {   // stage tile t+1; kick off load of tile t+2
            *(sh8*)&xb[nxt][sm * LDH + sk] = pack8(xg0, xg1);
            const int t2 = (t + 2 < 16) ? t + 2 : t;     // clamp; tail value unused
            const float* p = xrow + (size_t)t2 * (16 * HH);
            xg0 = *(const float4*)p;
            xg1 = *(const float4*)(p + 4);
        }
        sh8 xf[8];
#pragma unroll
        for (int kf = 0; kf < 8; ++kf)
            xf[kf] = *(const sh8*)&xb[cur][li * LDH + kf * 32 + lq * 8];

        f32x4 acc[2][2];
#pragma unroll
        for (int d = 0; d < 2; ++d)           // kf=0: C = bias (no mov copies)
#pragma unroll
            for (int nt = 0; nt < 2; ++nt)
                acc[d][nt] = __builtin_amdgcn_mfma_f32_16x16x32_bf16(
                    wf[d][nt][0], xf[0], bias4[d][nt], 0, 0, 0);
#pragma unroll
        for (int kf = 1; kf < 8; ++kf)
#pragma unroll
            for (int d = 0; d < 2; ++d)
#pragma unroll
                for (int nt = 0; nt < 2; ++nt)
                    acc[d][nt] = __builtin_amdgcn_mfma_f32_16x16x32_bf16(
                        wf[d][nt][kf], xf[kf], acc[d][nt], 0, 0, 0);

        if (perm) {   // coalesced: 1KB contiguous per wave per (d,nt)
#pragma unroll
            for (int nt = 0; nt < 2; ++nt) {
                *(f32x4*)(cp0 + (size_t)t * 8192 + nt * 256) = acc[0][nt];
                *(f32x4*)(cp1 + (size_t)t * 8192 + nt * 256) = acc[1][nt];
            }
        } else {      // canonical in-place (fallback)
            float* op = obase + (size_t)t * (16 * 512);
#pragma unroll
            for (int d = 0; d < 2; ++d)
#pragma unroll
                for (int nt = 0; nt < 2; ++nt)
                    *(f32x4*)(op + d * HH + nt * 16) = acc[d][nt];
        }
        bar_lds();
    }
}

// ---------------------------------------------------------------------------
// Phase B: h_t = tanh(xw_t + h_{t-1} @ Wh), scan over T.
// 16 blocks (8 batch-groups x 2 dirs) x 512 threads (8 waves, 32 cols/wave,
// 2 waves/SIMD). Lane owns batch row bbase+li, cols N0 + nt*16 + lq*4 (+0..3).
// xw read from permuted ws chunks (perm=1, coalesced) or in-place out (perm=0).
// ---------------------------------------------------------------------------
__global__ __launch_bounds__(512, 2) void rnn_recur(
    const float* __restrict__ Whf, const float* __restrict__ Whb,
    float* __restrict__ out, const float* __restrict__ xws, int perm)
{
    __shared__ __align__(16) unsigned short hb[2][16 * LDH];   // h state, bf16

    const int tid = threadIdx.x;
    const int w  = tid >> 6, l = tid & 63;
    const int li = l & 15, lq = l >> 4;
    const int dir   = blockIdx.x >> 3;
    const int g     = blockIdx.x & 7;
    const int bbase = g * 16;
    const float* Wh = dir ? Whb : Whf;
    const int N0 = w * 32;

    // A-operand fragments of Wh^T (64 VGPRs resident):
    // a[j] = Wh[k][n], k = kf*32+lq*8+j, n = N0 + nt*16 + li
    sh8 wfh[2][8];
#pragma unroll
    for (int nt = 0; nt < 2; ++nt)
#pragma unroll
        for (int kf = 0; kf < 8; ++kf) {
            sh8 t;
#pragma unroll
            for (int j = 0; j < 8; ++j)
                t[j] = (short)f2bf(Wh[(size_t)(kf * 32 + lq * 8 + j) * HH + N0 + nt * 16 + li]);
            wfh[nt][kf] = t;
        }

    // h0 = 0
    for (int i = tid; i < 16 * LDH / 2; i += 512) ((unsigned*)hb[0])[i] = 0u;

    const ptrdiff_t ostep = dir ? -(ptrdiff_t)(BB * 512) : (ptrdiff_t)(BB * 512);
    const int t0 = dir ? TT - 1 : 0;
    // lane's rolling out pointer (tanh store target, canonical layout)
    float* op = out + (size_t)t0 * (BB * 512)
                    + (size_t)(bbase + li) * 512 + dir * HH + N0 + lq * 4;
    float* fsp = out + (size_t)TT * BB * 512 + (size_t)dir * (BB * HH)
                     + (size_t)(bbase + li) * HH + N0 + lq * 4;

    // xw read pointer: permuted ws chunks (coalesced) or canonical out
    const float* pfb;        // xw(t0) lane address
    ptrdiff_t pstep;         // per-timestep delta (signed by dir)
    int ntoff;               // nt stride in floats
    if (perm) {
        pfb = xws + (size_t)(t0 * 8 + g) * 8192 + (size_t)dir * 4096
                  + w * 512 + (size_t)l * 4;
        pstep = dir ? -(ptrdiff_t)65536 : (ptrdiff_t)65536;
        ntoff = 256;
    } else {
        pfb = op;
        pstep = ostep;
        ntoff = 16;
    }

    // 4-deep xw prefetch in four NAMED register sets (no runtime indexing)
    f32x4 xA[2], xB[2], xC[2], xD[2];
#pragma unroll
    for (int nt = 0; nt < 2; ++nt) {
        xA[nt] = *(const f32x4*)(pfb + 0 * pstep + nt * ntoff);
        xB[nt] = *(const f32x4*)(pfb + 1 * pstep + nt * ntoff);
        xC[nt] = *(const f32x4*)(pfb + 2 * pstep + nt * ntoff);
        xD[nt] = *(const f32x4*)(pfb + 3 * pstep + nt * ntoff);
    }
    const float* pf = pfb + 4 * pstep;          // prefetch: xw(s+4)'s address
    const f32x4 zero4 = (f32x4){0.f, 0.f, 0.f, 0.f};   // persistent C-seed

    // LDS base pointers (u16 elements)
    const unsigned short* hr0 = &hb[0][li * LDH + lq * 8];        // + kf*32
    const unsigned short* hr1 = &hb[1][li * LDH + lq * 8];
    unsigned short*       hw0 = &hb[0][li * LDH + N0 + lq * 4];   // + nt*16
    unsigned short*       hw1 = &hb[1][li * LDH + N0 + lq * 4];

    bar_lds();

#define STEP(s_, HR, HW, XU)                                                    \
    do {                                                                        \
        sh8 hf[8];                                                              \
        _Pragma("unroll")                                                       \
        for (int kf = 0; kf < 8; ++kf)                                          \
            hf[kf] = *(const sh8*)(HR + kf * 32);                               \
        f32x4 acc[2], acd[2];                                                   \
        __builtin_amdgcn_s_setprio(1);                                          \
        _Pragma("unroll")                                                       \
        for (int nt = 0; nt < 2; ++nt) {  /* chain heads: C=xw and C=0 */       \
            acc[nt] = __builtin_amdgcn_mfma_f32_16x16x32_bf16(                  \
                wfh[nt][0], hf[0], XU[nt], 0, 0, 0);                            \
            acd[nt] = __builtin_amdgcn_mfma_f32_16x16x32_bf16(                  \
                wfh[nt][4], hf[4], zero4, 0, 0, 0);                             \
        }                                                                       \
        _Pragma("unroll")                                                       \
        for (int nt = 0; nt < 2; ++nt)   /* refill XU with xw(s+4) */           \
            XU[nt] = *(const f32x4*)(pf + nt * ntoff);                          \
        pf += ((s_) + 5 < TT) ? pstep : 0;   /* uniform clamp at tail */        \
        _Pragma("unroll")                                                       \
        for (int kf = 1; kf < 4; ++kf)                                          \
            _Pragma("unroll")                                                   \
            for (int nt = 0; nt < 2; ++nt) {                                    \
                acc[nt] = __builtin_amdgcn_mfma_f32_16x16x32_bf16(              \
                    wfh[nt][kf], hf[kf], acc[nt], 0, 0, 0);                     \
                acd[nt] = __builtin_amdgcn_mfma_f32_16x16x32_bf16(              \
                    wfh[nt][kf + 4], hf[kf + 4], acd[nt], 0, 0, 0);             \
            }                                                                   \
        __builtin_amdgcn_s_setprio(0);                                          \
        f32x4 vv[2];                                                            \
        _Pragma("unroll")                                                       \
        for (int nt = 0; nt < 2; ++nt) {                                        \
            f32x4 v;                                                            \
            v[0] = tanh5(acc[nt][0] + acd[nt][0]);                              \
            v[1] = tanh5(acc[nt][1] + acd[nt][1]);                              \
            v[2] = tanh5(acc[nt][2] + acd[nt][2]);                              \
            v[3] = tanh5(acc[nt][3] + acd[nt][3]);                              \
            vv[nt] = v;                                                         \
            *(f32x4*)(op + nt * 16) = v;                                        \
            unsigned plo = pk2bf(v[0], v[1]);                                   \
            unsigned phi = pk2bf(v[2], v[3]);                                   \
            *(uint2*)(HW + nt * 16) = make_uint2(plo, phi);                     \
        }                                                                       \
        if ((s_) == TT - 1) {                                                   \
            _Pragma("unroll")                                                   \
            for (int nt = 0; nt < 2; ++nt)                                      \
                *(f32x4*)(fsp + nt * 16) = vv[nt];                              \
        }                                                                       \
        op += ostep;                                                            \
        bar_lds();                                                              \
    } while (0)

    for (int s = 0; s < TT; s += 4) {
        STEP(s,     hr0, hw1, xA);
        STEP(s + 1, hr1, hw0, xB);
        STEP(s + 2, hr0, hw1, xC);
        STEP(s + 3, hr1, hw0, xD);
    }
#undef STEP
}

extern "C" void kernel_launch(void* const* d_in, const int* in_sizes, int n_in,
                              void* d_out, int out_size, void* d_ws, size_t ws_size,
                              hipStream_t stream)
{
    const float* x   = (const float*)d_in[0];
    const float* Wxf = (const float*)d_in[1];
    const float* Whf = (const float*)d_in[2];
    const float* bhf = (const float*)d_in[3];
    const float* Wxb = (const float*)d_in[4];
    const float* Whb = (const float*)d_in[5];
    const float* bhb = (const float*)d_in[6];

    const size_t XWBYTES = (size_t)TT * BB * 512 * 4;   // 134 MB
    const int perm = (d_ws != nullptr && ws_size >= XWBYTES) ? 1 : 0;
    float* xws = perm ? (float*)d_ws : (float*)d_out;

    hipLaunchKernelGGL(xw_precompute, dim3(256), dim3(512), 0, stream,
                       x, Wxf, bhf, Wxb, bhb, (float*)d_out, xws, perm);
    hipLaunchKernelGGL(rnn_recur, dim3(16), dim3(512), 0, stream,
                       Whf, Whb, (float*)d_out, xws, perm);
}